// Round 1
// baseline (646.399 us; speedup 1.0000x reference)
//
#include <hip/hip_runtime.h>
#include <stdint.h>

#define NROI 2000
#define MPAD 2048
#define KP   12544   // 256*49
#define N1   1024
#define NCLS 81
#define NBOX 324
#define N3   405
#define N3P  448
#define BN_EPS 0.001f

typedef __attribute__((ext_vector_type(8))) short bf16x8;
typedef __attribute__((ext_vector_type(4))) float f32x4;

__device__ inline unsigned short f2bf(float f) {
  union { float f; unsigned u; } v; v.f = f;
  unsigned r = v.u + 0x7fffu + ((v.u >> 16) & 1u);
  return (unsigned short)(r >> 16);
}

__device__ inline void gld16(const unsigned short* g, unsigned short* l) {
  __builtin_amdgcn_global_load_lds(
      (const __attribute__((address_space(1))) void*)g,
      (__attribute__((address_space(3))) void*)l, 16, 0, 0);
}

// ---------------- small param prep: BN folding + bias concat ----------------
__global__ void prep_small(const float* c1b, const float* g1, const float* b1,
                           const float* m1, const float* v1,
                           const float* c2b, const float* g2, const float* b2,
                           const float* m2, const float* v2,
                           const float* lb, const float* bb,
                           float* s1, float* t1, float* s2, float* t2, float* b3) {
  int i = blockIdx.x * 256 + threadIdx.x;
  if (i < 1024) {
    float s = g1[i] * rsqrtf(v1[i] + BN_EPS);
    s1[i] = s;
    t1[i] = (c1b[i] - m1[i]) * s + b1[i];
    float ss = g2[i] * rsqrtf(v2[i] + BN_EPS);
    s2[i] = ss;
    t2[i] = (c2b[i] - m2[i]) * ss + b2[i];
  }
  if (i < N3P) b3[i] = (i < NCLS) ? lb[i] : (i < N3 ? bb[i - NCLS] : 0.0f);
}

// ---------------- weight conversions ----------------
__global__ void cvt_w2(const float* w, unsigned short* o) {
  int stride = gridDim.x * blockDim.x;
  for (int j = blockIdx.x * blockDim.x + threadIdx.x; j < 1024 * 1024; j += stride)
    o[j] = f2bf(w[j]);
}

__global__ void pack_w3(const float* lw, const float* bw, unsigned short* o) {
  int row = blockIdx.x;  // 0..447
  for (int k = threadIdx.x; k < 1024; k += blockDim.x) {
    float v = (row < NCLS) ? lw[row * 1024 + k]
                           : (row < N3 ? bw[(row - NCLS) * 1024 + k] : 0.0f);
    o[row * 1024 + k] = f2bf(v);
  }
}

// conv1_w [o][c][hw]  ->  w1p [o][hw*256 + c]  (bf16), k-order = (hw, c)
__global__ void repack_w1(const float* w1, unsigned short* o) {
  __shared__ unsigned short s[KP];
  int oc = blockIdx.x;
  const float* src = w1 + (size_t)oc * KP;
  for (int j = threadIdx.x; j < KP; j += 256) s[j] = f2bf(src[j]);  // s[c*49+hw]
  __syncthreads();
  unsigned short* dst = o + (size_t)oc * KP;
  int c = threadIdx.x;
  for (int j = 0; j < 49; ++j) dst[j * 256 + c] = s[c * 49 + j];
}

// ---------------- ROI Align: pooled [n][hw][c] bf16, rows >= NROI zeroed ----
__global__ void roi_align(const float* __restrict__ p2, const float* __restrict__ p3,
                          const float* __restrict__ p4, const float* __restrict__ p5,
                          const float* __restrict__ rois, unsigned short* __restrict__ pooled) {
  int n = blockIdx.x;
  int c = threadIdx.x;  // 0..255 == channel
  unsigned short* out = pooled + (size_t)n * KP;
  if (n >= NROI) {
    for (int j = 0; j < 49; ++j) out[j * 256 + c] = 0;
    return;
  }
  float x1 = rois[n * 4 + 0], y1 = rois[n * 4 + 1];
  float x2 = rois[n * 4 + 2], y2 = rois[n * 4 + 3];
  float area = (y2 - y1) * (x2 - x1);
  float lvl_f = rintf(log2f(sqrtf(area) / 224.0f)) + 4.0f;
  lvl_f = fminf(fmaxf(lvl_f, 2.0f), 5.0f);
  int lvl = (int)lvl_f;
  const float* f;
  int H;
  if (lvl == 2)      { f = p2; H = 256; }
  else if (lvl == 3) { f = p3; H = 128; }
  else if (lvl == 4) { f = p4; H = 64;  }
  else               { f = p5; H = 32;  }
  int W = H;
  const float inv = 1.0f / 1024.0f;
  float yn1 = y1 * inv, xn1 = x1 * inv, yn2 = y2 * inv, xn2 = x2 * inv;
  float hs = (yn2 - yn1) * (H - 1);
  float ws = (xn2 - xn1) * (W - 1);
  float yb = yn1 * (H - 1);
  float xb = xn1 * (W - 1);
  const float* fc_ = f + (size_t)c * H * W;
  for (int py = 0; py < 7; ++py) {
    float ty = (float)py / 6.0f;
    float ysv = yb + ty * hs;
    float y0f = floorf(ysv);
    float ly = ysv - y0f;
    int y0 = (int)y0f; y0 = min(max(y0, 0), H - 1);
    int y1i = min(y0 + 1, H - 1);
    for (int px = 0; px < 7; ++px) {
      float tx = (float)px / 6.0f;
      float xsv = xb + tx * ws;
      float x0f = floorf(xsv);
      float lx = xsv - x0f;
      int x0 = (int)x0f; x0 = min(max(x0, 0), W - 1);
      int x1i = min(x0 + 1, W - 1);
      float v00 = fc_[y0 * W + x0],  v01 = fc_[y0 * W + x1i];
      float v10 = fc_[y1i * W + x0], v11 = fc_[y1i * W + x1i];
      float v = v00 * (1 - ly) * (1 - lx) + v01 * (1 - ly) * lx +
                v10 * ly * (1 - lx) + v11 * ly * lx;
      out[(py * 7 + px) * 256 + c] = f2bf(v);
    }
  }
}

// ---------------- bf16 MFMA GEMM, B^T input: C[m][n] = sum_k A[m][k]*B[n][k]
// MODE 1: out_bf16[m*ldo+n] = (m<validM) ? bf16(relu(acc*sc[n]+sh[n])) : 0
// MODE 2: out_f32 [m*ldo+n] = acc + sh[n]
template <int MODE>
__global__ __launch_bounds__(256) void gemm_bt(
    const unsigned short* __restrict__ A, const unsigned short* __restrict__ B,
    int M, int N, int K,
    const float* __restrict__ sc, const float* __restrict__ sh,
    unsigned short* __restrict__ outb, float* __restrict__ outf,
    int validM, int ldo) {
  __shared__ unsigned short As[64 * 32];
  __shared__ unsigned short Bs[64 * 32];
  int bm0 = blockIdx.y * 64;
  int bn0 = blockIdx.x * 64;
  int t = threadIdx.x;
  int lane = t & 63, w = t >> 6;
  int wm = (w & 1) * 32, wn = (w >> 1) * 32;
  int ln = lane & 15, q = lane >> 4;

  const unsigned short* ga = A + (size_t)(bm0 + (t >> 2)) * K + (t & 3) * 8;
  const unsigned short* gb = B + (size_t)(bn0 + (t >> 2)) * K + (t & 3) * 8;
  unsigned short* la = &As[t * 8];
  unsigned short* lb = &Bs[t * 8];

  f32x4 acc00 = {0.f, 0.f, 0.f, 0.f}, acc01 = {0.f, 0.f, 0.f, 0.f};
  f32x4 acc10 = {0.f, 0.f, 0.f, 0.f}, acc11 = {0.f, 0.f, 0.f, 0.f};

  for (int k0 = 0; k0 < K; k0 += 32) {
    gld16(ga + k0, la);
    gld16(gb + k0, lb);
    __syncthreads();  // compiler drains vmcnt before s_barrier
    bf16x8 a0 = *(const bf16x8*)&As[(wm + ln) * 32 + q * 8];
    bf16x8 a1 = *(const bf16x8*)&As[(wm + 16 + ln) * 32 + q * 8];
    bf16x8 b0 = *(const bf16x8*)&Bs[(wn + ln) * 32 + q * 8];
    bf16x8 b1 = *(const bf16x8*)&Bs[(wn + 16 + ln) * 32 + q * 8];
    acc00 = __builtin_amdgcn_mfma_f32_16x16x32_bf16(a0, b0, acc00, 0, 0, 0);
    acc01 = __builtin_amdgcn_mfma_f32_16x16x32_bf16(a0, b1, acc01, 0, 0, 0);
    acc10 = __builtin_amdgcn_mfma_f32_16x16x32_bf16(a1, b0, acc10, 0, 0, 0);
    acc11 = __builtin_amdgcn_mfma_f32_16x16x32_bf16(a1, b1, acc11, 0, 0, 0);
    __syncthreads();
  }

  f32x4 accs[2][2] = {{acc00, acc01}, {acc10, acc11}};
#pragma unroll
  for (int i = 0; i < 2; ++i)
#pragma unroll
    for (int j = 0; j < 2; ++j)
#pragma unroll
      for (int r = 0; r < 4; ++r) {
        int m = bm0 + wm + i * 16 + q * 4 + r;
        int n = bn0 + wn + j * 16 + ln;
        float v = accs[i][j][r];
        if (MODE == 1) {
          float o = fmaxf(v * sc[n] + sh[n], 0.0f);
          outb[(size_t)m * ldo + n] = (m < validM) ? f2bf(o) : (unsigned short)0;
        } else {
          outf[(size_t)m * ldo + n] = v + sh[n];
        }
      }
}

// ---------------- softmax + output scatter ----------------
__global__ void head(const float* __restrict__ fc3, float* __restrict__ out) {
  int r = blockIdx.x;   // 0..1999
  int t = threadIdx.x;  // 0..63
  const float* row = fc3 + (size_t)r * N3P;
  float v0 = (t < NCLS) ? row[t] : -INFINITY;
  float v1 = (t + 64 < NCLS) ? row[t + 64] : -INFINITY;
  float m = fmaxf(v0, v1);
#pragma unroll
  for (int o = 32; o > 0; o >>= 1) m = fmaxf(m, __shfl_xor(m, o, 64));
  float e0 = (t < NCLS) ? expf(v0 - m) : 0.0f;
  float e1 = (t + 64 < NCLS) ? expf(v1 - m) : 0.0f;
  float s = e0 + e1;
#pragma unroll
  for (int o = 32; o > 0; o >>= 1) s += __shfl_xor(s, o, 64);
  float invs = 1.0f / s;
  float* ol = out + (size_t)r * NCLS;
  float* op = out + 162000 + (size_t)r * NCLS;
  float* ob = out + 324000 + (size_t)r * NBOX;
  if (t < NCLS) { ol[t] = v0; op[t] = e0 * invs; }
  if (t + 64 < NCLS) { ol[t + 64] = v1; op[t + 64] = e1 * invs; }
  for (int j = t; j < NBOX; j += 64) ob[j] = row[NCLS + j];
}

extern "C" void kernel_launch(void* const* d_in, const int* in_sizes, int n_in,
                              void* d_out, int out_size, void* d_ws, size_t ws_size,
                              hipStream_t stream) {
  const float* p2  = (const float*)d_in[0];
  const float* p3  = (const float*)d_in[1];
  const float* p4  = (const float*)d_in[2];
  const float* p5  = (const float*)d_in[3];
  const float* roi = (const float*)d_in[4];
  const float* c1w = (const float*)d_in[5];
  const float* c1b = (const float*)d_in[6];
  const float* g1  = (const float*)d_in[7];
  const float* b1  = (const float*)d_in[8];
  const float* m1  = (const float*)d_in[9];
  const float* v1  = (const float*)d_in[10];
  const float* c2w = (const float*)d_in[11];
  const float* c2b = (const float*)d_in[12];
  const float* g2  = (const float*)d_in[13];
  const float* b2  = (const float*)d_in[14];
  const float* m2  = (const float*)d_in[15];
  const float* v2  = (const float*)d_in[16];
  const float* lw  = (const float*)d_in[17];
  const float* lb  = (const float*)d_in[18];
  const float* bw  = (const float*)d_in[19];
  const float* bb  = (const float*)d_in[20];
  float* out = (float*)d_out;

  char* ws = (char*)d_ws;
  size_t off = 0;
  auto alloc = [&](size_t bytes) {
    void* p = ws + off;
    off = (off + bytes + 255) & ~(size_t)255;
    return p;
  };
  unsigned short* pooled = (unsigned short*)alloc((size_t)MPAD * KP * 2);
  unsigned short* w1p    = (unsigned short*)alloc((size_t)N1 * KP * 2);
  unsigned short* w2b    = (unsigned short*)alloc((size_t)N1 * N1 * 2);
  unsigned short* w3b    = (unsigned short*)alloc((size_t)N3P * N1 * 2);
  unsigned short* a2     = (unsigned short*)alloc((size_t)MPAD * N1 * 2);
  unsigned short* shd    = (unsigned short*)alloc((size_t)MPAD * N1 * 2);
  float* fc3 = (float*)alloc((size_t)MPAD * N3P * 4);
  float* s1  = (float*)alloc(1024 * 4);
  float* t1  = (float*)alloc(1024 * 4);
  float* s2  = (float*)alloc(1024 * 4);
  float* t2  = (float*)alloc(1024 * 4);
  float* b3  = (float*)alloc(N3P * 4);

  prep_small<<<4, 256, 0, stream>>>(c1b, g1, b1, m1, v1, c2b, g2, b2, m2, v2,
                                    lb, bb, s1, t1, s2, t2, b3);
  cvt_w2<<<512, 256, 0, stream>>>(c2w, w2b);
  pack_w3<<<N3P, 256, 0, stream>>>(lw, bw, w3b);
  repack_w1<<<N1, 256, 0, stream>>>(c1w, w1p);
  roi_align<<<MPAD, 256, 0, stream>>>(p2, p3, p4, p5, roi, pooled);

  // GEMM1: [2048 x 12544] x [1024 x 12544]^T -> BN1+ReLU -> a2 (bf16)
  gemm_bt<1><<<dim3(N1 / 64, MPAD / 64), 256, 0, stream>>>(
      pooled, w1p, MPAD, N1, KP, s1, t1, a2, nullptr, NROI, N1);
  // GEMM2: [2048 x 1024] x [1024 x 1024]^T -> BN2+ReLU -> shd (bf16)
  gemm_bt<1><<<dim3(N1 / 64, MPAD / 64), 256, 0, stream>>>(
      a2, w2b, MPAD, N1, N1, s2, t2, shd, nullptr, NROI, N1);
  // GEMM3: [2048 x 1024] x [448 x 1024]^T + bias -> fc3 (f32)
  gemm_bt<2><<<dim3(N3P / 64, MPAD / 64), 256, 0, stream>>>(
      shd, w3b, MPAD, N3P, N1, nullptr, b3, nullptr, fc3, NROI, N3P);

  head<<<NROI, 64, 0, stream>>>(fc3, out);
}

// Round 2
// 452.427 us; speedup vs baseline: 1.4287x; 1.4287x over previous
//
#include <hip/hip_runtime.h>
#include <stdint.h>

#define NROI 2000
#define MPAD 2048
#define KP   12544   // 256*49
#define N1   1024
#define NCLS 81
#define NBOX 324
#define N3   405
#define N3P  448
#define BN_EPS 0.001f

typedef __attribute__((ext_vector_type(8))) short bf16x8;
typedef __attribute__((ext_vector_type(4))) float f32x4;

__device__ inline unsigned short f2bf(float f) {
  union { float f; unsigned u; } v; v.f = f;
  unsigned r = v.u + 0x7fffu + ((v.u >> 16) & 1u);
  return (unsigned short)(r >> 16);
}

__device__ inline float bf2f(unsigned short h) {
  union { unsigned u; float f; } v; v.u = (unsigned)h << 16; return v.f;
}

__device__ inline void gld16(const unsigned short* g, unsigned short* l) {
  __builtin_amdgcn_global_load_lds(
      (const __attribute__((address_space(1))) void*)g,
      (__attribute__((address_space(3))) void*)l, 16, 0, 0);
}

// ---------------- small param prep: BN folding + bias concat ----------------
__global__ void prep_small(const float* c1b, const float* g1, const float* b1,
                           const float* m1, const float* v1,
                           const float* c2b, const float* g2, const float* b2,
                           const float* m2, const float* v2,
                           const float* lb, const float* bb,
                           float* s1, float* t1, float* s2, float* t2, float* b3) {
  int i = blockIdx.x * 256 + threadIdx.x;
  if (i < 1024) {
    float s = g1[i] * rsqrtf(v1[i] + BN_EPS);
    s1[i] = s;
    t1[i] = (c1b[i] - m1[i]) * s + b1[i];
    float ss = g2[i] * rsqrtf(v2[i] + BN_EPS);
    s2[i] = ss;
    t2[i] = (c2b[i] - m2[i]) * ss + b2[i];
  }
  if (i < N3P) b3[i] = (i < NCLS) ? lb[i] : (i < N3 ? bb[i - NCLS] : 0.0f);
}

// ---------------- weight conversions ----------------
__global__ void cvt_w2(const float* w, unsigned short* o) {
  int stride = gridDim.x * blockDim.x;
  for (int j = blockIdx.x * blockDim.x + threadIdx.x; j < 1024 * 1024; j += stride)
    o[j] = f2bf(w[j]);
}

__global__ void pack_w3(const float* lw, const float* bw, unsigned short* o) {
  int row = blockIdx.x;  // 0..447
  for (int k = threadIdx.x; k < 1024; k += blockDim.x) {
    float v = (row < NCLS) ? lw[row * 1024 + k]
                           : (row < N3 ? bw[(row - NCLS) * 1024 + k] : 0.0f);
    o[row * 1024 + k] = f2bf(v);
  }
}

// conv1_w [o][c][hw]  ->  w1p [o][hw*256 + c]  (bf16), k-order = (hw, c)
__global__ void repack_w1(const float* w1, unsigned short* o) {
  __shared__ unsigned short s[KP];
  int oc = blockIdx.x;
  const float* src = w1 + (size_t)oc * KP;
  for (int j = threadIdx.x; j < KP; j += 256) s[j] = f2bf(src[j]);  // s[c*49+hw]
  __syncthreads();
  unsigned short* dst = o + (size_t)oc * KP;
  int c = threadIdx.x;
  for (int j = 0; j < 49; ++j) dst[j * 256 + c] = s[c * 49 + j];
}

// ---------------- fmap transpose: [256][HW] f32 -> [HW][256] bf16 ----------
// 64-pixel tiles via LDS; stride 258 shorts = 129 dwords -> bank step 1 on
// px-indexed writes (conflict-free), 2-way on c-indexed reads (free).
__global__ void transpose_fmap(const float* __restrict__ src,
                               unsigned short* __restrict__ dst, int HW) {
  __shared__ unsigned short s[64][258];
  int p0 = blockIdx.x * 64;
  int t = threadIdx.x;
  int px = t & 63;   // lane = pixel
  int cq = t >> 6;   // wave = channel phase
  for (int c = cq; c < 256; c += 4)
    s[px][c] = f2bf(src[(size_t)c * HW + p0 + px]);
  __syncthreads();
  for (int p = 0; p < 64; ++p)
    dst[(size_t)(p0 + p) * 256 + t] = s[p][t];
}

// ---------------- ROI Align v2: gather from [HW][256] bf16 maps ------------
// pooled [n][hw][c] bf16, rows >= NROI zeroed. Per corner a wave reads 64
// consecutive bf16 (128 B, one transaction) instead of 64 cache lines.
__global__ void roi_align2(const unsigned short* __restrict__ f2t,
                           const unsigned short* __restrict__ f3t,
                           const unsigned short* __restrict__ f4t,
                           const unsigned short* __restrict__ f5t,
                           const float* __restrict__ rois,
                           unsigned short* __restrict__ pooled) {
  int n = blockIdx.x;
  int c = threadIdx.x;  // 0..255 == channel
  unsigned short* out = pooled + (size_t)n * KP;
  if (n >= NROI) {
    for (int j = 0; j < 49; ++j) out[j * 256 + c] = 0;
    return;
  }
  float x1 = rois[n * 4 + 0], y1 = rois[n * 4 + 1];
  float x2 = rois[n * 4 + 2], y2 = rois[n * 4 + 3];
  float area = (y2 - y1) * (x2 - x1);
  float lvl_f = rintf(log2f(sqrtf(area) / 224.0f)) + 4.0f;
  lvl_f = fminf(fmaxf(lvl_f, 2.0f), 5.0f);
  int lvl = (int)lvl_f;
  const unsigned short* f;
  int H;
  if (lvl == 2)      { f = f2t; H = 256; }
  else if (lvl == 3) { f = f3t; H = 128; }
  else if (lvl == 4) { f = f4t; H = 64;  }
  else               { f = f5t; H = 32;  }
  int W = H;
  const float inv = 1.0f / 1024.0f;
  float yn1 = y1 * inv, xn1 = x1 * inv, yn2 = y2 * inv, xn2 = x2 * inv;
  float hs = (yn2 - yn1) * (H - 1);
  float ws = (xn2 - xn1) * (W - 1);
  float yb = yn1 * (H - 1);
  float xb = xn1 * (W - 1);

  int x0a[7], x1a[7];
  float lxa[7];
#pragma unroll
  for (int px = 0; px < 7; ++px) {
    float xsv = xb + ((float)px / 6.0f) * ws;
    float x0f = floorf(xsv);
    lxa[px] = xsv - x0f;
    int x0 = (int)x0f; x0 = min(max(x0, 0), W - 1);
    x0a[px] = x0;
    x1a[px] = min(x0 + 1, W - 1);
  }
  for (int py = 0; py < 7; ++py) {
    float ysv = yb + ((float)py / 6.0f) * hs;
    float y0f = floorf(ysv);
    float ly = ysv - y0f;
    int y0 = (int)y0f; y0 = min(max(y0, 0), H - 1);
    int y1i = min(y0 + 1, H - 1);
    const unsigned short* r0 = f + ((size_t)y0 * W) * 256 + c;
    const unsigned short* r1 = f + ((size_t)y1i * W) * 256 + c;
#pragma unroll
    for (int px = 0; px < 7; ++px) {
      int x0 = x0a[px] * 256, x1i = x1a[px] * 256;
      float lx = lxa[px];
      float v00 = bf2f(r0[x0]), v01 = bf2f(r0[x1i]);
      float v10 = bf2f(r1[x0]), v11 = bf2f(r1[x1i]);
      float top = v00 + lx * (v01 - v00);
      float bot = v10 + lx * (v11 - v10);
      out[(py * 7 + px) * 256 + c] = f2bf(top + ly * (bot - top));
    }
  }
}

// ---------------- bf16 MFMA GEMM, B^T input: C[m][n] = sum_k A[m][k]*B[n][k]
// MODE 1: out_bf16[m*ldo+n] = (m<validM) ? bf16(relu(acc*sc[n]+sh[n])) : 0
// MODE 2: out_f32 [m*ldo+n] = acc + sh[n]
template <int MODE>
__global__ __launch_bounds__(256) void gemm_bt(
    const unsigned short* __restrict__ A, const unsigned short* __restrict__ B,
    int M, int N, int K,
    const float* __restrict__ sc, const float* __restrict__ sh,
    unsigned short* __restrict__ outb, float* __restrict__ outf,
    int validM, int ldo) {
  __shared__ unsigned short As[64 * 32];
  __shared__ unsigned short Bs[64 * 32];
  int bm0 = blockIdx.y * 64;
  int bn0 = blockIdx.x * 64;
  int t = threadIdx.x;
  int lane = t & 63, w = t >> 6;
  int wm = (w & 1) * 32, wn = (w >> 1) * 32;
  int ln = lane & 15, q = lane >> 4;

  const unsigned short* ga = A + (size_t)(bm0 + (t >> 2)) * K + (t & 3) * 8;
  const unsigned short* gb = B + (size_t)(bn0 + (t >> 2)) * K + (t & 3) * 8;
  unsigned short* la = &As[t * 8];
  unsigned short* lb = &Bs[t * 8];

  f32x4 acc00 = {0.f, 0.f, 0.f, 0.f}, acc01 = {0.f, 0.f, 0.f, 0.f};
  f32x4 acc10 = {0.f, 0.f, 0.f, 0.f}, acc11 = {0.f, 0.f, 0.f, 0.f};

  for (int k0 = 0; k0 < K; k0 += 32) {
    gld16(ga + k0, la);
    gld16(gb + k0, lb);
    __syncthreads();  // compiler drains vmcnt before s_barrier
    bf16x8 a0 = *(const bf16x8*)&As[(wm + ln) * 32 + q * 8];
    bf16x8 a1 = *(const bf16x8*)&As[(wm + 16 + ln) * 32 + q * 8];
    bf16x8 b0 = *(const bf16x8*)&Bs[(wn + ln) * 32 + q * 8];
    bf16x8 b1 = *(const bf16x8*)&Bs[(wn + 16 + ln) * 32 + q * 8];
    acc00 = __builtin_amdgcn_mfma_f32_16x16x32_bf16(a0, b0, acc00, 0, 0, 0);
    acc01 = __builtin_amdgcn_mfma_f32_16x16x32_bf16(a0, b1, acc01, 0, 0, 0);
    acc10 = __builtin_amdgcn_mfma_f32_16x16x32_bf16(a1, b0, acc10, 0, 0, 0);
    acc11 = __builtin_amdgcn_mfma_f32_16x16x32_bf16(a1, b1, acc11, 0, 0, 0);
    __syncthreads();
  }

  f32x4 accs[2][2] = {{acc00, acc01}, {acc10, acc11}};
#pragma unroll
  for (int i = 0; i < 2; ++i)
#pragma unroll
    for (int j = 0; j < 2; ++j)
#pragma unroll
      for (int r = 0; r < 4; ++r) {
        int m = bm0 + wm + i * 16 + q * 4 + r;
        int n = bn0 + wn + j * 16 + ln;
        float v = accs[i][j][r];
        if (MODE == 1) {
          float o = fmaxf(v * sc[n] + sh[n], 0.0f);
          outb[(size_t)m * ldo + n] = (m < validM) ? f2bf(o) : (unsigned short)0;
        } else {
          outf[(size_t)m * ldo + n] = v + sh[n];
        }
      }
}

// ---------------- softmax + output scatter ----------------
__global__ void head(const float* __restrict__ fc3, float* __restrict__ out) {
  int r = blockIdx.x;   // 0..1999
  int t = threadIdx.x;  // 0..63
  const float* row = fc3 + (size_t)r * N3P;
  float v0 = (t < NCLS) ? row[t] : -INFINITY;
  float v1 = (t + 64 < NCLS) ? row[t + 64] : -INFINITY;
  float m = fmaxf(v0, v1);
#pragma unroll
  for (int o = 32; o > 0; o >>= 1) m = fmaxf(m, __shfl_xor(m, o, 64));
  float e0 = (t < NCLS) ? expf(v0 - m) : 0.0f;
  float e1 = (t + 64 < NCLS) ? expf(v1 - m) : 0.0f;
  float s = e0 + e1;
#pragma unroll
  for (int o = 32; o > 0; o >>= 1) s += __shfl_xor(s, o, 64);
  float invs = 1.0f / s;
  float* ol = out + (size_t)r * NCLS;
  float* op = out + 162000 + (size_t)r * NCLS;
  float* ob = out + 324000 + (size_t)r * NBOX;
  if (t < NCLS) { ol[t] = v0; op[t] = e0 * invs; }
  if (t + 64 < NCLS) { ol[t + 64] = v1; op[t + 64] = e1 * invs; }
  for (int j = t; j < NBOX; j += 64) ob[j] = row[NCLS + j];
}

extern "C" void kernel_launch(void* const* d_in, const int* in_sizes, int n_in,
                              void* d_out, int out_size, void* d_ws, size_t ws_size,
                              hipStream_t stream) {
  const float* p2  = (const float*)d_in[0];
  const float* p3  = (const float*)d_in[1];
  const float* p4  = (const float*)d_in[2];
  const float* p5  = (const float*)d_in[3];
  const float* roi = (const float*)d_in[4];
  const float* c1w = (const float*)d_in[5];
  const float* c1b = (const float*)d_in[6];
  const float* g1  = (const float*)d_in[7];
  const float* b1  = (const float*)d_in[8];
  const float* m1  = (const float*)d_in[9];
  const float* v1  = (const float*)d_in[10];
  const float* c2w = (const float*)d_in[11];
  const float* c2b = (const float*)d_in[12];
  const float* g2  = (const float*)d_in[13];
  const float* b2  = (const float*)d_in[14];
  const float* m2  = (const float*)d_in[15];
  const float* v2  = (const float*)d_in[16];
  const float* lw  = (const float*)d_in[17];
  const float* lb  = (const float*)d_in[18];
  const float* bw  = (const float*)d_in[19];
  const float* bb  = (const float*)d_in[20];
  float* out = (float*)d_out;

  char* ws = (char*)d_ws;
  size_t off = 0;
  auto alloc = [&](size_t bytes) {
    void* p = ws + off;
    off = (off + bytes + 255) & ~(size_t)255;
    return p;
  };
  unsigned short* pooled = (unsigned short*)alloc((size_t)MPAD * KP * 2);
  unsigned short* w1p    = (unsigned short*)alloc((size_t)N1 * KP * 2);
  unsigned short* w2b    = (unsigned short*)alloc((size_t)N1 * N1 * 2);
  unsigned short* w3b    = (unsigned short*)alloc((size_t)N3P * N1 * 2);
  unsigned short* a2     = (unsigned short*)alloc((size_t)MPAD * N1 * 2);
  unsigned short* shd    = (unsigned short*)alloc((size_t)MPAD * N1 * 2);
  float* fc3 = (float*)alloc((size_t)MPAD * N3P * 4);
  unsigned short* f2t = (unsigned short*)alloc((size_t)256 * 256 * 256 * 2);
  unsigned short* f3t = (unsigned short*)alloc((size_t)128 * 128 * 256 * 2);
  unsigned short* f4t = (unsigned short*)alloc((size_t)64 * 64 * 256 * 2);
  unsigned short* f5t = (unsigned short*)alloc((size_t)32 * 32 * 256 * 2);
  float* s1  = (float*)alloc(1024 * 4);
  float* t1  = (float*)alloc(1024 * 4);
  float* s2  = (float*)alloc(1024 * 4);
  float* t2  = (float*)alloc(1024 * 4);
  float* b3  = (float*)alloc(N3P * 4);

  prep_small<<<4, 256, 0, stream>>>(c1b, g1, b1, m1, v1, c2b, g2, b2, m2, v2,
                                    lb, bb, s1, t1, s2, t2, b3);
  cvt_w2<<<512, 256, 0, stream>>>(c2w, w2b);
  pack_w3<<<N3P, 256, 0, stream>>>(lw, bw, w3b);
  repack_w1<<<N1, 256, 0, stream>>>(c1w, w1p);

  transpose_fmap<<<1024, 256, 0, stream>>>(p2, f2t, 256 * 256);
  transpose_fmap<<<256,  256, 0, stream>>>(p3, f3t, 128 * 128);
  transpose_fmap<<<64,   256, 0, stream>>>(p4, f4t, 64 * 64);
  transpose_fmap<<<16,   256, 0, stream>>>(p5, f5t, 32 * 32);

  roi_align2<<<MPAD, 256, 0, stream>>>(f2t, f3t, f4t, f5t, roi, pooled);

  // GEMM1: [2048 x 12544] x [1024 x 12544]^T -> BN1+ReLU -> a2 (bf16)
  gemm_bt<1><<<dim3(N1 / 64, MPAD / 64), 256, 0, stream>>>(
      pooled, w1p, MPAD, N1, KP, s1, t1, a2, nullptr, NROI, N1);
  // GEMM2: [2048 x 1024] x [1024 x 1024]^T -> BN2+ReLU -> shd (bf16)
  gemm_bt<1><<<dim3(N1 / 64, MPAD / 64), 256, 0, stream>>>(
      a2, w2b, MPAD, N1, N1, s2, t2, shd, nullptr, NROI, N1);
  // GEMM3: [2048 x 1024] x [448 x 1024]^T + bias -> fc3 (f32)
  gemm_bt<2><<<dim3(N3P / 64, MPAD / 64), 256, 0, stream>>>(
      shd, w3b, MPAD, N3P, N1, nullptr, b3, nullptr, fc3, NROI, N3P);

  head<<<NROI, 64, 0, stream>>>(fc3, out);
}

// Round 3
// 394.859 us; speedup vs baseline: 1.6370x; 1.1458x over previous
//
#include <hip/hip_runtime.h>
#include <stdint.h>

#define NROI 2000
#define MPAD 2048
#define KP   12544   // 256*49
#define N1   1024
#define NCLS 81
#define NBOX 324
#define N3   405
#define N3P  448
#define BN_EPS 0.001f
#define KSPLIT 4

typedef __attribute__((ext_vector_type(8))) short bf16x8;
typedef __attribute__((ext_vector_type(4))) float f32x4;

__device__ inline unsigned short f2bf(float f) {
  union { float f; unsigned u; } v; v.f = f;
  unsigned r = v.u + 0x7fffu + ((v.u >> 16) & 1u);
  return (unsigned short)(r >> 16);
}

__device__ inline float bf2f(unsigned short h) {
  union { unsigned u; float f; } v; v.u = (unsigned)h << 16; return v.f;
}

__device__ inline void gld16(const unsigned short* g, unsigned short* l) {
  __builtin_amdgcn_global_load_lds(
      (const __attribute__((address_space(1))) void*)g,
      (__attribute__((address_space(3))) void*)l, 16, 0, 0);
}

// ---------------- small param prep: BN folding + bias concat ----------------
__global__ void prep_small(const float* c1b, const float* g1, const float* b1,
                           const float* m1, const float* v1,
                           const float* c2b, const float* g2, const float* b2,
                           const float* m2, const float* v2,
                           const float* lb, const float* bb,
                           float* s1, float* t1, float* s2, float* t2, float* b3) {
  int i = blockIdx.x * 256 + threadIdx.x;
  if (i < 1024) {
    float s = g1[i] * rsqrtf(v1[i] + BN_EPS);
    s1[i] = s;
    t1[i] = (c1b[i] - m1[i]) * s + b1[i];
    float ss = g2[i] * rsqrtf(v2[i] + BN_EPS);
    s2[i] = ss;
    t2[i] = (c2b[i] - m2[i]) * ss + b2[i];
  }
  if (i < N3P) b3[i] = (i < NCLS) ? lb[i] : (i < N3 ? bb[i - NCLS] : 0.0f);
}

// ---------------- weight conversions ----------------
__global__ void cvt_w2(const float* w, unsigned short* o) {
  int stride = gridDim.x * blockDim.x;
  for (int j = blockIdx.x * blockDim.x + threadIdx.x; j < 1024 * 1024; j += stride)
    o[j] = f2bf(w[j]);
}

__global__ void pack_w3(const float* lw, const float* bw, unsigned short* o) {
  int row = blockIdx.x;  // 0..447
  for (int k = threadIdx.x; k < 1024; k += blockDim.x) {
    float v = (row < NCLS) ? lw[row * 1024 + k]
                           : (row < N3 ? bw[(row - NCLS) * 1024 + k] : 0.0f);
    o[row * 1024 + k] = f2bf(v);
  }
}

// conv1_w [o][c][hw]  ->  w1p [o][hw*256 + c]  (bf16), k-order = (hw, c)
__global__ void repack_w1(const float* w1, unsigned short* o) {
  __shared__ unsigned short s[KP];
  int oc = blockIdx.x;
  const float* src = w1 + (size_t)oc * KP;
  for (int j = threadIdx.x; j < KP; j += 256) s[j] = f2bf(src[j]);  // s[c*49+hw]
  __syncthreads();
  unsigned short* dst = o + (size_t)oc * KP;
  int c = threadIdx.x;
  for (int j = 0; j < 49; ++j) dst[j * 256 + c] = s[c * 49 + j];
}

// ---------------- fmap transpose: [256][HW] f32 -> [HW][256] bf16 ----------
__global__ void transpose_fmap(const float* __restrict__ src,
                               unsigned short* __restrict__ dst, int HW) {
  __shared__ unsigned short s[64][258];
  int p0 = blockIdx.x * 64;
  int t = threadIdx.x;
  int px = t & 63;   // lane = pixel
  int cq = t >> 6;   // wave = channel phase
  for (int c = cq; c < 256; c += 4)
    s[px][c] = f2bf(src[(size_t)c * HW + p0 + px]);
  __syncthreads();
  for (int p = 0; p < 64; ++p)
    dst[(size_t)(p0 + p) * 256 + t] = s[p][t];
}

// ---------------- ROI Align v2: gather from [HW][256] bf16 maps ------------
__global__ void roi_align2(const unsigned short* __restrict__ f2t,
                           const unsigned short* __restrict__ f3t,
                           const unsigned short* __restrict__ f4t,
                           const unsigned short* __restrict__ f5t,
                           const float* __restrict__ rois,
                           unsigned short* __restrict__ pooled) {
  int n = blockIdx.x;
  int c = threadIdx.x;  // 0..255 == channel
  unsigned short* out = pooled + (size_t)n * KP;
  if (n >= NROI) {
    for (int j = 0; j < 49; ++j) out[j * 256 + c] = 0;
    return;
  }
  float x1 = rois[n * 4 + 0], y1 = rois[n * 4 + 1];
  float x2 = rois[n * 4 + 2], y2 = rois[n * 4 + 3];
  float area = (y2 - y1) * (x2 - x1);
  float lvl_f = rintf(log2f(sqrtf(area) / 224.0f)) + 4.0f;
  lvl_f = fminf(fmaxf(lvl_f, 2.0f), 5.0f);
  int lvl = (int)lvl_f;
  const unsigned short* f;
  int H;
  if (lvl == 2)      { f = f2t; H = 256; }
  else if (lvl == 3) { f = f3t; H = 128; }
  else if (lvl == 4) { f = f4t; H = 64;  }
  else               { f = f5t; H = 32;  }
  int W = H;
  const float inv = 1.0f / 1024.0f;
  float yn1 = y1 * inv, xn1 = x1 * inv, yn2 = y2 * inv, xn2 = x2 * inv;
  float hs = (yn2 - yn1) * (H - 1);
  float ws = (xn2 - xn1) * (W - 1);
  float yb = yn1 * (H - 1);
  float xb = xn1 * (W - 1);

  int x0a[7], x1a[7];
  float lxa[7];
#pragma unroll
  for (int px = 0; px < 7; ++px) {
    float xsv = xb + ((float)px / 6.0f) * ws;
    float x0f = floorf(xsv);
    lxa[px] = xsv - x0f;
    int x0 = (int)x0f; x0 = min(max(x0, 0), W - 1);
    x0a[px] = x0;
    x1a[px] = min(x0 + 1, W - 1);
  }
  for (int py = 0; py < 7; ++py) {
    float ysv = yb + ((float)py / 6.0f) * hs;
    float y0f = floorf(ysv);
    float ly = ysv - y0f;
    int y0 = (int)y0f; y0 = min(max(y0, 0), H - 1);
    int y1i = min(y0 + 1, H - 1);
    const unsigned short* r0 = f + ((size_t)y0 * W) * 256 + c;
    const unsigned short* r1 = f + ((size_t)y1i * W) * 256 + c;
#pragma unroll
    for (int px = 0; px < 7; ++px) {
      int x0 = x0a[px] * 256, x1i = x1a[px] * 256;
      float lx = lxa[px];
      float v00 = bf2f(r0[x0]), v01 = bf2f(r0[x1i]);
      float v10 = bf2f(r1[x0]), v11 = bf2f(r1[x1i]);
      float top = v00 + lx * (v01 - v00);
      float bot = v10 + lx * (v11 - v10);
      out[(py * 7 + px) * 256 + c] = f2bf(top + ly * (bot - top));
    }
  }
}

// ---------------- GEMM1 split-K: 128x128 tile, 4 waves, 4x4 MFMA/wave ------
// C_part[kz][m][n] = sum over K-chunk kz of A[m][k]*B[n][k]
__global__ __launch_bounds__(256) void gemm1_sk(
    const unsigned short* __restrict__ A, const unsigned short* __restrict__ B,
    float* __restrict__ part) {
  __shared__ unsigned short As[128 * 32];
  __shared__ unsigned short Bs[128 * 32];
  int bm0 = blockIdx.y * 128;
  int bn0 = blockIdx.x * 128;
  int kz = blockIdx.z;
  int t = threadIdx.x;
  int lane = t & 63, w = t >> 6;
  int wm = (w & 1) * 64, wn = (w >> 1) * 64;
  int ln = lane & 15, q = lane >> 4;

  const int KC = KP / KSPLIT;  // 3136 = 98 * 32
  const unsigned short* ga0 = A + (size_t)(bm0 + (t >> 2)) * KP + kz * KC + (t & 3) * 8;
  const unsigned short* ga1 = ga0 + (size_t)64 * KP;
  const unsigned short* gb0 = B + (size_t)(bn0 + (t >> 2)) * KP + kz * KC + (t & 3) * 8;
  const unsigned short* gb1 = gb0 + (size_t)64 * KP;
  unsigned short* la0 = &As[t * 8];
  unsigned short* la1 = &As[t * 8 + 2048];
  unsigned short* lb0 = &Bs[t * 8];
  unsigned short* lb1 = &Bs[t * 8 + 2048];

  f32x4 acc[4][4] = {};

  for (int k0 = 0; k0 < KC; k0 += 32) {
    gld16(ga0 + k0, la0);
    gld16(ga1 + k0, la1);
    gld16(gb0 + k0, lb0);
    gld16(gb1 + k0, lb1);
    __syncthreads();
    bf16x8 af[4], bfr[4];
#pragma unroll
    for (int i = 0; i < 4; ++i) {
      af[i]  = *(const bf16x8*)&As[(wm + i * 16 + ln) * 32 + q * 8];
      bfr[i] = *(const bf16x8*)&Bs[(wn + i * 16 + ln) * 32 + q * 8];
    }
#pragma unroll
    for (int i = 0; i < 4; ++i)
#pragma unroll
      for (int j = 0; j < 4; ++j)
        acc[i][j] = __builtin_amdgcn_mfma_f32_16x16x32_bf16(af[i], bfr[j], acc[i][j], 0, 0, 0);
    __syncthreads();
  }

  float* po = part + (size_t)kz * MPAD * N1;
#pragma unroll
  for (int i = 0; i < 4; ++i)
#pragma unroll
    for (int j = 0; j < 4; ++j)
#pragma unroll
      for (int r = 0; r < 4; ++r) {
        int m = bm0 + wm + i * 16 + q * 4 + r;
        int n = bn0 + wn + j * 16 + ln;
        po[(size_t)m * N1 + n] = acc[i][j][r];
      }
}

// ---------------- split-K reduce + BN1 + ReLU + bf16 cast ------------------
__global__ void reduce_sk(const float* __restrict__ part,
                          const float* __restrict__ sc, const float* __restrict__ sh,
                          unsigned short* __restrict__ outb) {
  const size_t P = (size_t)MPAD * N1;           // 2M floats per partial
  int idx = blockIdx.x * 256 + threadIdx.x;     // 0 .. 512K-1 (float4 index)
  const float4* p0 = (const float4*)part;
  float4 v = p0[idx];
  float4 v1 = p0[idx + P / 4];
  float4 v2 = p0[idx + 2 * (P / 4)];
  float4 v3 = p0[idx + 3 * (P / 4)];
  v.x += v1.x + v2.x + v3.x;
  v.y += v1.y + v2.y + v3.y;
  v.z += v1.z + v2.z + v3.z;
  v.w += v1.w + v2.w + v3.w;
  int n0 = (idx * 4) & (N1 - 1);
  int m = idx >> 8;  // (idx*4)/1024
  ushort4 o;
  if (m < NROI) {
    o.x = f2bf(fmaxf(v.x * sc[n0 + 0] + sh[n0 + 0], 0.0f));
    o.y = f2bf(fmaxf(v.y * sc[n0 + 1] + sh[n0 + 1], 0.0f));
    o.z = f2bf(fmaxf(v.z * sc[n0 + 2] + sh[n0 + 2], 0.0f));
    o.w = f2bf(fmaxf(v.w * sc[n0 + 3] + sh[n0 + 3], 0.0f));
  } else {
    o = make_ushort4(0, 0, 0, 0);
  }
  *(ushort4*)(outb + (size_t)idx * 4) = o;
}

// ---------------- bf16 MFMA GEMM (64x64 tile), B^T input -------------------
// MODE 1: out_bf16 = relu(acc*sc[n]+sh[n]) (rows>=validM zeroed)
// MODE 2: out_f32  = acc + sh[n]
template <int MODE>
__global__ __launch_bounds__(256) void gemm_bt(
    const unsigned short* __restrict__ A, const unsigned short* __restrict__ B,
    int M, int N, int K,
    const float* __restrict__ sc, const float* __restrict__ sh,
    unsigned short* __restrict__ outb, float* __restrict__ outf,
    int validM, int ldo) {
  __shared__ unsigned short As[64 * 32];
  __shared__ unsigned short Bs[64 * 32];
  int bm0 = blockIdx.y * 64;
  int bn0 = blockIdx.x * 64;
  int t = threadIdx.x;
  int lane = t & 63, w = t >> 6;
  int wm = (w & 1) * 32, wn = (w >> 1) * 32;
  int ln = lane & 15, q = lane >> 4;

  const unsigned short* ga = A + (size_t)(bm0 + (t >> 2)) * K + (t & 3) * 8;
  const unsigned short* gb = B + (size_t)(bn0 + (t >> 2)) * K + (t & 3) * 8;
  unsigned short* la = &As[t * 8];
  unsigned short* lb = &Bs[t * 8];

  f32x4 acc00 = {0.f, 0.f, 0.f, 0.f}, acc01 = {0.f, 0.f, 0.f, 0.f};
  f32x4 acc10 = {0.f, 0.f, 0.f, 0.f}, acc11 = {0.f, 0.f, 0.f, 0.f};

  for (int k0 = 0; k0 < K; k0 += 32) {
    gld16(ga + k0, la);
    gld16(gb + k0, lb);
    __syncthreads();
    bf16x8 a0 = *(const bf16x8*)&As[(wm + ln) * 32 + q * 8];
    bf16x8 a1 = *(const bf16x8*)&As[(wm + 16 + ln) * 32 + q * 8];
    bf16x8 b0 = *(const bf16x8*)&Bs[(wn + ln) * 32 + q * 8];
    bf16x8 b1 = *(const bf16x8*)&Bs[(wn + 16 + ln) * 32 + q * 8];
    acc00 = __builtin_amdgcn_mfma_f32_16x16x32_bf16(a0, b0, acc00, 0, 0, 0);
    acc01 = __builtin_amdgcn_mfma_f32_16x16x32_bf16(a0, b1, acc01, 0, 0, 0);
    acc10 = __builtin_amdgcn_mfma_f32_16x16x32_bf16(a1, b0, acc10, 0, 0, 0);
    acc11 = __builtin_amdgcn_mfma_f32_16x16x32_bf16(a1, b1, acc11, 0, 0, 0);
    __syncthreads();
  }

  f32x4 accs[2][2] = {{acc00, acc01}, {acc10, acc11}};
#pragma unroll
  for (int i = 0; i < 2; ++i)
#pragma unroll
    for (int j = 0; j < 2; ++j)
#pragma unroll
      for (int r = 0; r < 4; ++r) {
        int m = bm0 + wm + i * 16 + q * 4 + r;
        int n = bn0 + wn + j * 16 + ln;
        float v = accs[i][j][r];
        if (MODE == 1) {
          float o = fmaxf(v * sc[n] + sh[n], 0.0f);
          outb[(size_t)m * ldo + n] = (m < validM) ? f2bf(o) : (unsigned short)0;
        } else {
          outf[(size_t)m * ldo + n] = v + sh[n];
        }
      }
}

// ---------------- softmax + output scatter ----------------
__global__ void head(const float* __restrict__ fc3, float* __restrict__ out) {
  int r = blockIdx.x;   // 0..1999
  int t = threadIdx.x;  // 0..63
  const float* row = fc3 + (size_t)r * N3P;
  float v0 = (t < NCLS) ? row[t] : -INFINITY;
  float v1 = (t + 64 < NCLS) ? row[t + 64] : -INFINITY;
  float m = fmaxf(v0, v1);
#pragma unroll
  for (int o = 32; o > 0; o >>= 1) m = fmaxf(m, __shfl_xor(m, o, 64));
  float e0 = (t < NCLS) ? expf(v0 - m) : 0.0f;
  float e1 = (t + 64 < NCLS) ? expf(v1 - m) : 0.0f;
  float s = e0 + e1;
#pragma unroll
  for (int o = 32; o > 0; o >>= 1) s += __shfl_xor(s, o, 64);
  float invs = 1.0f / s;
  float* ol = out + (size_t)r * NCLS;
  float* op = out + 162000 + (size_t)r * NCLS;
  float* ob = out + 324000 + (size_t)r * NBOX;
  if (t < NCLS) { ol[t] = v0; op[t] = e0 * invs; }
  if (t + 64 < NCLS) { ol[t + 64] = v1; op[t + 64] = e1 * invs; }
  for (int j = t; j < NBOX; j += 64) ob[j] = row[NCLS + j];
}

extern "C" void kernel_launch(void* const* d_in, const int* in_sizes, int n_in,
                              void* d_out, int out_size, void* d_ws, size_t ws_size,
                              hipStream_t stream) {
  const float* p2  = (const float*)d_in[0];
  const float* p3  = (const float*)d_in[1];
  const float* p4  = (const float*)d_in[2];
  const float* p5  = (const float*)d_in[3];
  const float* roi = (const float*)d_in[4];
  const float* c1w = (const float*)d_in[5];
  const float* c1b = (const float*)d_in[6];
  const float* g1  = (const float*)d_in[7];
  const float* b1  = (const float*)d_in[8];
  const float* m1  = (const float*)d_in[9];
  const float* v1  = (const float*)d_in[10];
  const float* c2w = (const float*)d_in[11];
  const float* c2b = (const float*)d_in[12];
  const float* g2  = (const float*)d_in[13];
  const float* b2  = (const float*)d_in[14];
  const float* m2  = (const float*)d_in[15];
  const float* v2  = (const float*)d_in[16];
  const float* lw  = (const float*)d_in[17];
  const float* lb  = (const float*)d_in[18];
  const float* bw  = (const float*)d_in[19];
  const float* bb  = (const float*)d_in[20];
  float* out = (float*)d_out;

  char* ws = (char*)d_ws;
  size_t off = 0;
  auto alloc = [&](size_t bytes) {
    void* p = ws + off;
    off = (off + bytes + 255) & ~(size_t)255;
    return p;
  };
  unsigned short* pooled = (unsigned short*)alloc((size_t)MPAD * KP * 2);
  unsigned short* w1p    = (unsigned short*)alloc((size_t)N1 * KP * 2);
  unsigned short* w2b    = (unsigned short*)alloc((size_t)N1 * N1 * 2);
  unsigned short* w3b    = (unsigned short*)alloc((size_t)N3P * N1 * 2);
  unsigned short* a2     = (unsigned short*)alloc((size_t)MPAD * N1 * 2);
  unsigned short* shd    = (unsigned short*)alloc((size_t)MPAD * N1 * 2);
  float* fc3 = (float*)alloc((size_t)MPAD * N3P * 4);
  float* part = (float*)alloc((size_t)KSPLIT * MPAD * N1 * 4);  // 32 MB
  unsigned short* f2t = (unsigned short*)alloc((size_t)256 * 256 * 256 * 2);
  unsigned short* f3t = (unsigned short*)alloc((size_t)128 * 128 * 256 * 2);
  unsigned short* f4t = (unsigned short*)alloc((size_t)64 * 64 * 256 * 2);
  unsigned short* f5t = (unsigned short*)alloc((size_t)32 * 32 * 256 * 2);
  float* s1  = (float*)alloc(1024 * 4);
  float* t1  = (float*)alloc(1024 * 4);
  float* s2  = (float*)alloc(1024 * 4);
  float* t2  = (float*)alloc(1024 * 4);
  float* b3  = (float*)alloc(N3P * 4);

  prep_small<<<4, 256, 0, stream>>>(c1b, g1, b1, m1, v1, c2b, g2, b2, m2, v2,
                                    lb, bb, s1, t1, s2, t2, b3);
  cvt_w2<<<512, 256, 0, stream>>>(c2w, w2b);
  pack_w3<<<N3P, 256, 0, stream>>>(lw, bw, w3b);
  repack_w1<<<N1, 256, 0, stream>>>(c1w, w1p);

  transpose_fmap<<<1024, 256, 0, stream>>>(p2, f2t, 256 * 256);
  transpose_fmap<<<256,  256, 0, stream>>>(p3, f3t, 128 * 128);
  transpose_fmap<<<64,   256, 0, stream>>>(p4, f4t, 64 * 64);
  transpose_fmap<<<16,   256, 0, stream>>>(p5, f5t, 32 * 32);

  roi_align2<<<MPAD, 256, 0, stream>>>(f2t, f3t, f4t, f5t, roi, pooled);

  // GEMM1: [2048 x 12544] x [1024 x 12544]^T split-K=4 -> part -> BN1+ReLU -> a2
  gemm1_sk<<<dim3(N1 / 128, MPAD / 128, KSPLIT), 256, 0, stream>>>(pooled, w1p, part);
  reduce_sk<<<MPAD * N1 / 1024, 256, 0, stream>>>(part, s1, t1, a2);

  // GEMM2: [2048 x 1024] x [1024 x 1024]^T -> BN2+ReLU -> shd (bf16)
  gemm_bt<1><<<dim3(N1 / 64, MPAD / 64), 256, 0, stream>>>(
      a2, w2b, MPAD, N1, N1, s2, t2, shd, nullptr, NROI, N1);
  // GEMM3: [2048 x 1024] x [448 x 1024]^T + bias -> fc3 (f32)
  gemm_bt<2><<<dim3(N3P / 64, MPAD / 64), 256, 0, stream>>>(
      shd, w3b, MPAD, N3P, N1, nullptr, b3, nullptr, fc3, NROI, N3P);

  head<<<NROI, 64, 0, stream>>>(fc3, out);
}